// Round 10
// baseline (528.305 us; speedup 1.0000x reference)
//
#include <hip/hip_runtime.h>
#include <hip/hip_bf16.h>
#include <stdint.h>

typedef __attribute__((ext_vector_type(4))) float f32x4;
typedef __attribute__((ext_vector_type(8))) short s16x8;
typedef unsigned short u16;
typedef unsigned int u32;

#define BM 128
#define BK 64

// round-to-nearest-even f32 -> bf16 (bit pattern)
__device__ __forceinline__ u16 f32_to_bf16(float f) {
    uint32_t u = __float_as_uint(f);
    u = u + 0x7FFFu + ((u >> 16) & 1u);
    return (u16)(u >> 16);
}

__device__ __forceinline__ void gld_lds16(const void* g, void* l) {
    __builtin_amdgcn_global_load_lds(
        (const __attribute__((address_space(1))) uint32_t*)g,
        (__attribute__((address_space(3))) uint32_t*)l,
        16, 0, 0);
}

// Prep fusion: one read of the fp32 input produces BOTH the straight
// bf16 form and the transposed bf16 form.
__global__ void stein_prep_sq(const float* __restrict__ in, u16* __restrict__ outB,
                              u16* __restrict__ outT, int N2) {
    __shared__ float tile[32][33];
    const int tx = threadIdx.x, ty = threadIdx.y;     // 32 x 8
    const int c0 = blockIdx.x * 32, r0 = blockIdx.y * 32;
#pragma unroll
    for (int i = 0; i < 32; i += 8) {
        float v = in[(size_t)(r0 + ty + i) * N2 + (c0 + tx)];
        outB[(size_t)(r0 + ty + i) * N2 + (c0 + tx)] = f32_to_bf16(v);
        tile[ty + i][tx] = v;
    }
    __syncthreads();
#pragma unroll
    for (int i = 0; i < 32; i += 8)
        outT[(size_t)(c0 + ty + i) * N2 + (r0 + tx)] = f32_to_bf16(tile[tx][ty + i]);
}

// Rect prep: in is R x C; outB = straight bf16 (R x C); outT = transpose
// (C x R) with row stride ldoT (left half of the K-concat buffers).
__global__ void stein_prep_rect(const float* __restrict__ in, u16* __restrict__ outB,
                                u16* __restrict__ outT, int R, int C, int ldoT) {
    __shared__ float tile[32][33];
    const int tx = threadIdx.x, ty = threadIdx.y;     // 32 x 8
    const int c0 = blockIdx.x * 32, r0 = blockIdx.y * 32;
#pragma unroll
    for (int i = 0; i < 32; i += 8) {
        float v = in[(size_t)(r0 + ty + i) * C + (c0 + tx)];
        outB[(size_t)(r0 + ty + i) * C + (c0 + tx)] = f32_to_bf16(v);
        tile[ty + i][tx] = v;
    }
    __syncthreads();
#pragma unroll
    for (int i = 0; i < 32; i += 8)
        outT[(size_t)(c0 + ty + i) * ldoT + (r0 + tx)] = f32_to_bf16(tile[tx][ty + i]);
}

// Runtime-descriptor GEMM op: C[m,n] = sum_k U[m,k] V[n,k]  (NT, bf16 in).
struct GemmOp {
    const u16* U; const u16* V;
    const float* Add;
    u16* OutB; u16* OutT; float* OutF;
    int K, ldu, ldv, N, ldo;
};

// R22 = R20 kernel verbatim; occupancy change only. R21 post-mortem:
// dead-register asm touches clobber reallocated VGPRs on retire (crash);
// and counter math shows NOTHING saturates (MFMA work 13.8us of a 63.5us
// dispatch; L2/HBM each ~4.5x headroom) -> not latency, not BW: occupancy.
// Per SIMD: 2 waves x 32 MFMA x 19.4 cyc = 1242 cyc of a 4760-cyc tile
// cadence = 26% = measured MfmaUtil. Fix: BNT=64 tile for the dominant
// multi-op dispatches -> LDS 48KB/block -> 3 blocks/CU (144<=160KB), grids
// (16,32,z) = 1024 blocks so count supports it. 12 waves/CU = 3/SIMD.
// Cost: FLOP/staged-byte 64 -> 42.7 (+50% L2 demand, ~21us floor — OK).
//  - BNT=128 kept for nothing by default now; template retained.
//  - BNT=64 path already verified in R20 (d0b/XT/Fin); new combo OutT+64
//    audited (c_<64, T idx < 24576, full 64x128 coverage).
// R20 retained: XCD chunking (square ops), OutT LDS bounce (WRITE 61->37),
// staged A AND B (global per-lane B gather = 2x slower, R19), A/B bank
// swizzle (0 conflicts): phys chunk p of row r holds logical p ^ (r&7);
// readers use (s*4+(lane>>4)) ^ (lane&7).
template <int BNT>
__global__ __launch_bounds__(256, 2) void stein_gemm_nt2(GemmOp op0, GemmOp op1,
                                                         GemmOp op2, GemmOp op3,
                                                         GemmOp op4) {
    constexpr int NJ = BNT / 32;              // acc cols per wave (4 or 2)
    const int z = blockIdx.z;
    const GemmOp op = (z == 0) ? op0 : (z == 1) ? op1 : (z == 2) ? op2
                      : (z == 3) ? op3 : op4;
    int bm = blockIdx.x, bn = blockIdx.y;
    if (op.N >= 16 * BNT) {                   // square op: XCD chunking
        const int orig = (int)blockIdx.x + ((int)blockIdx.y << 4);
        const int xcd = orig & 7, idx = orig >> 3;
        constexpr int BNCH = (BNT == 128) ? 8 : 16;   // bn chunk width
        bm = (xcd & 3) * 4 + (idx & 3);
        bn = (xcd >> 2) * BNCH + (idx >> 2);
    }
    if (bn * BNT >= op.N) return;             // rectangular (N=512) ops

    __shared__ alignas(16) short SMEM[2 * BM * BK + 2 * BNT * BK];
    short* Us0 = SMEM;                        // 2 x BM*BK
    short* Vs0 = SMEM + 2 * BM * BK;          // 2 x BNT*BK

    const int t = threadIdx.x;
    const int wave = t >> 6;
    const int lane = t & 63;
    const int wm = (wave >> 1) * 64;
    const int wn = (wave & 1) * (BNT / 2);

    // staging: wave w covers A rows [32w,32w+32) (4 DMA ops) and B rows
    // [w*BNT/4, +BNT/4) (BNT/32 DMA ops); 8 rows x 128 B per op.
    const int lrow8 = lane >> 3;                  // 0..7
    const int lchunk = (lane & 7) ^ lrow8;        // swizzled source chunk
    const u16* gU = op.U + (size_t)(bm * BM + wave * 32 + lrow8) * op.ldu + lchunk * 8;
    const u16* gV = op.V + (size_t)(bn * BNT + wave * (BNT / 4) + lrow8) * op.ldv + lchunk * 8;
    short* sU = Us0 + (wave * 32) * BK;
    short* sV = Vs0 + (wave * (BNT / 4)) * BK;
    const int bufU = BM * BK;                     // elements per buffer
    const int bufV = BNT * BK;

    f32x4 acc[4][NJ];
#pragma unroll
    for (int i = 0; i < 4; ++i)
#pragma unroll
        for (int j = 0; j < NJ; ++j) acc[i][j] = (f32x4){0.f, 0.f, 0.f, 0.f};

    const int arow = wm + (lane & 15);
    const int brow = wn + (lane & 15);

    // prologue: stage tile 0 into buffer 0
#pragma unroll
    for (int j = 0; j < 4; ++j)
        gld_lds16(gU + (size_t)(8 * j) * op.ldu, sU + j * 512);
#pragma unroll
    for (int j = 0; j < BNT / 32; ++j)
        gld_lds16(gV + (size_t)(8 * j) * op.ldv, sV + j * 512);

    int buf = 0;
    for (int kk = 0; kk < op.K; kk += BK) {
        __syncthreads();   // buffer `buf` staged; prior reads of buf^1 done
        if (kk + BK < op.K) {
            const int kn = kk + BK;
            const int bo = buf ^ 1;
#pragma unroll
            for (int j = 0; j < 4; ++j)
                gld_lds16(gU + (size_t)(8 * j) * op.ldu + kn, sU + bo * bufU + j * 512);
#pragma unroll
            for (int j = 0; j < BNT / 32; ++j)
                gld_lds16(gV + (size_t)(8 * j) * op.ldv + kn, sV + bo * bufV + j * 512);
        }
#pragma unroll
        for (int s = 0; s < 2; ++s) {
            const int cx = (s * 4 + (lane >> 4)) ^ (lane & 7);   // phys chunk
            s16x8 af[4], bfr[NJ];
#pragma unroll
            for (int i = 0; i < 4; ++i)
                af[i] = ((const s16x8*)(Us0 + (size_t)buf * bufU))[(arow + i * 16) * (BK / 8) + cx];
#pragma unroll
            for (int j = 0; j < NJ; ++j)
                bfr[j] = ((const s16x8*)(Vs0 + (size_t)buf * bufV))[(brow + j * 16) * (BK / 8) + cx];
#pragma unroll
            for (int i = 0; i < 4; ++i)
#pragma unroll
                for (int j = 0; j < NJ; ++j)
                    acc[i][j] = __builtin_amdgcn_mfma_f32_16x16x32_bf16(
                        af[i], bfr[j], acc[i][j], 0, 0, 0);
        }
        buf ^= 1;
    }

    // ---- epilogue ----  C/D layout: col=lane&15, row=(lane>>4)*4+r
    const int ldo = op.ldo;
    const int ccol = lane & 15;
    const int crow = (lane >> 4) * 4;

    // pass 1: row-major outputs straight from registers (+ optional Add)
    if (op.OutB || op.OutF) {
#pragma unroll
        for (int i = 0; i < 4; ++i) {
#pragma unroll
            for (int j = 0; j < NJ; ++j) {
                const int gr0 = bm * BM + wm + i * 16 + crow;
                const int gc = bn * BNT + wn + j * 16 + ccol;
                float v[4];
#pragma unroll
                for (int r = 0; r < 4; ++r) {
                    v[r] = acc[i][j][r];
                    if (op.Add) v[r] += op.Add[(size_t)(gr0 + r) * ldo + gc];
                }
                if (op.OutB) {
#pragma unroll
                    for (int r = 0; r < 4; ++r)
                        op.OutB[(size_t)(gr0 + r) * ldo + gc] = f32_to_bf16(v[r]);
                }
                if (op.OutF) {
#pragma unroll
                    for (int r = 0; r < 4; ++r)
                        op.OutF[(size_t)(gr0 + r) * ldo + gc] = v[r];
                }
            }
        }
    }

    // pass 2: transposed bf16 via LDS bounce (staging LDS is dead now).
    // T[col][row], stride 132 u16 (bank spread). Coalesced 16 B/lane rows.
    if (op.OutT) {
        __syncthreads();                   // all K-loop LDS reads complete
        u16* T = (u16*)SMEM;               // BNT*132*2 B <= SMEM
#pragma unroll
        for (int i = 0; i < 4; ++i) {
#pragma unroll
            for (int j = 0; j < NJ; ++j) {
                const int c_ = wn + j * 16 + ccol;
                const int r_ = wm + i * 16 + crow;      // multiple of 4
                uint2 w;
                w.x = (u32)f32_to_bf16(acc[i][j][0]) | ((u32)f32_to_bf16(acc[i][j][1]) << 16);
                w.y = (u32)f32_to_bf16(acc[i][j][2]) | ((u32)f32_to_bf16(acc[i][j][3]) << 16);
                *(uint2*)&T[c_ * 132 + r_] = w;
            }
        }
        __syncthreads();
        const int cpart = t >> 4;          // 0..15: column within pass
        const int m = t & 15;              // 16 B chunk along the row
#pragma unroll
        for (int k2 = 0; k2 < BNT / 16; ++k2) {
            const int c_ = k2 * 16 + cpart;
            uint2 x = *(const uint2*)&T[c_ * 132 + m * 8];
            uint2 y = *(const uint2*)&T[c_ * 132 + m * 8 + 4];
            uint4 w; w.x = x.x; w.y = x.y; w.z = y.x; w.w = y.y;
            *(uint4*)&op.OutT[(size_t)(bn * BNT + c_) * ldo + bm * BM + m * 8] = w;
        }
    }
}

static inline GemmOp mkop(const u16* U, const u16* V, int K, int ldu, int ldv,
                          const float* Add, u16* OutB, u16* OutT, float* OutF,
                          int N = 2048, int ldo = 2048) {
    GemmOp o;
    o.U = U; o.V = V; o.Add = Add; o.OutB = OutB; o.OutT = OutT; o.OutF = OutF;
    o.K = K; o.ldu = ldu; o.ldv = ldv; o.N = N; o.ldo = ldo;
    return o;
}

extern "C" void kernel_launch(void* const* d_in, const int* in_sizes, int n_in,
                              void* d_out, int out_size, void* d_ws, size_t ws_size,
                              hipStream_t stream) {
    const float* A = (const float*)d_in[0];     // (2048, 2048)
    const float* A_F = (const float*)d_in[1];   // (2048, 2048)
    const float* C = (const float*)d_in[2];     // (512, 2048)
    const float* C_F = (const float*)d_in[3];   // (512, 2048)
    const int n = 2048, p = 512;
    (void)in_sizes; (void)n_in; (void)out_size; (void)ws_size;

    char* ws = (char*)d_ws;
    const size_t MB = 1u << 20;
    // ---- Smith squaring, 5 levels -> S_32 (tail bound: see R12 notes;
    // absmax 0.5 measured, threshold 2.33).
    // d0b-fold: R_1 = [CFT|W1] [CT|Y]^T in ONE K=1024 GEMM.
    // XT computed transpose-free via operand swap:
    //   (R A)^T = NT-GEMM(U = A^T, V = R)  -> plain OutB store.
    // Asq swapped to (U=A^T, V=A) so d1's two z's share the U stream:
    //   OutB = (A^2)^T, OutT = A^2.
    u16* AT   = (u16*)(ws + 0 * MB);    // A^T  bf16  (A_0 transposed form)
    u16* Ab   = (u16*)(ws + 8 * MB);    // A    bf16  (A_0 row form)
    u16* AFT  = (u16*)(ws + 16 * MB);   // B=A_F^T row bf16 (B_0 row form)
    u16* AFb  = (u16*)(ws + 24 * MB);   // A_F  bf16  (B_0 transposed form)
    u16* WYU  = (u16*)(ws + 32 * MB);   // 2048x1024: [CFT | W1=B C_F^T]
    u16* WYV  = (u16*)(ws + 36 * MB);   // 2048x1024: [CT  | Y=A^T C^T]
    u16* XT   = (u16*)(ws + 32 * MB);   // (R A_i)^T — overlaps WYU/WYV (dead after d0b)
    float* R32 = (float*)(ws + 40 * MB);// running R fp32
    u16* Rb   = (u16*)(ws + 56 * MB);   // running R bf16 row
    u16* CFb  = (u16*)(ws + 64 * MB);   // C_F bf16 row (level 0 only)
    u16* Cb   = (u16*)(ws + 66 * MB);   // C   bf16 row (level 0 only)
    u16* Tb1  = (u16*)(ws + 68 * MB);   // ping-pong set 1: B_i row
    u16* TbT1 = (u16*)(ws + 76 * MB);   //                  B_i^T
    u16* Ub1  = (u16*)(ws + 84 * MB);   //                  A_i row
    u16* UbT1 = (u16*)(ws + 92 * MB);   //                  A_i^T   (top = 100 MB)

    dim3 tb(32, 8);
    stein_prep_sq<<<dim3(64, 64), tb, 0, stream>>>(A, Ab, AT, n);
    stein_prep_sq<<<dim3(64, 64), tb, 0, stream>>>(A_F, AFb, AFT, n);
    stein_prep_rect<<<dim3(64, 16), tb, 0, stream>>>(C_F, CFb, WYU, p, n, 2 * p);
    stein_prep_rect<<<dim3(64, 16), tb, 0, stream>>>(C, Cb, WYV, p, n, 2 * p);

    u16* Tb[2]  = {AFT, Tb1};
    u16* TbT[2] = {AFb, TbT1};
    u16* Ub[2]  = {Ab, Ub1};
    u16* UbT[2] = {AT, UbT1};

    dim3 blk(256);
    // BNT=64 grids: (16,32) per op -> multi-op dispatches reach 1024 blocks
    // = 3 blocks/CU (LDS-capped), single-op = 512 blocks = 2/CU.
    dim3 g2(16, 32, 2), g4(16, 32, 4), gs(16, 32, 1);

    // d0 (z=4): level-0 independent ops. Long K=2048 small-N ops at LOW z
    // (dispatched first) so stragglers are short.
    {
        GemmOp oW1  = mkop(AFT, CFb, n, n, n, nullptr, WYU + p, nullptr, nullptr, p, 2 * p);
        GemmOp oY   = mkop(AT, Cb, n, n, n, nullptr, WYV + p, nullptr, nullptr, p, 2 * p);
        GemmOp oAsq = mkop(AT, Ab, n, n, n, nullptr, UbT1, Ub1, nullptr);   // swapped
        GemmOp oBsq = mkop(AFT, AFb, n, n, n, nullptr, Tb1, TbT1, nullptr);
        stein_gemm_nt2<64><<<g4, blk, 0, stream>>>(oW1, oY, oAsq, oBsq, oBsq);
    }
    // d0b: R_1 = [CFT|W1] [CT|Y]^T  (K=1024 concat = RHS + B RHS A)
    {
        GemmOp oR1 = mkop(WYU, WYV, 2 * p, 2 * p, 2 * p, nullptr, Rb, nullptr, R32);
        stein_gemm_nt2<64><<<gs, blk, 0, stream>>>(oR1, oR1, oR1, oR1, oR1);
    }

    // levels 1..3: full doubling, stream-sharing pairing.
    // R_j = S_{2^j}; after level 3: R_4 = S_16, A_4 = A^16 in set 0.
    // Level 3 drops dead outputs (level 4 needs only UbT[0] and Tb[0]).
    for (int i = 1; i < 4; ++i) {
        const int c = i & 1, nx = c ^ 1;
        // d1: {XT = (R A_i)^T via swap, Asq swapped} — shared U = A_i^T.
        GemmOp oXT = mkop(UbT[c], Rb, n, n, n, nullptr, XT, nullptr, nullptr);
        GemmOp oAsq = mkop(UbT[c], Ub[c], n, n, n, nullptr, UbT[nx],
                           (i == 3) ? nullptr : Ub[nx], nullptr);
        stein_gemm_nt2<64><<<g2, blk, 0, stream>>>(oXT, oAsq, oAsq, oAsq, oAsq);
        // d2: {Rup = B_i X + R, Bsq = B_i^2} — shared U stream = B_i.
        GemmOp oRup = mkop(Tb[c], XT, n, n, n, R32, Rb, nullptr, R32);
        GemmOp oBsq = mkop(Tb[c], TbT[c], n, n, n, nullptr, Tb[nx],
                           (i == 3) ? nullptr : TbT[nx], nullptr);
        stein_gemm_nt2<64><<<g2, blk, 0, stream>>>(oRup, oBsq, oBsq, oBsq, oBsq);
    }

    // level 4 (final): S_32 = R_4 + B_4 (R_4 A_4) -> d_out. A_4/B_4 in set 0.
    {
        GemmOp oXT = mkop(UbT[0], Rb, n, n, n, nullptr, XT, nullptr, nullptr);
        stein_gemm_nt2<64><<<gs, blk, 0, stream>>>(oXT, oXT, oXT, oXT, oXT);
        GemmOp oFin = mkop(Tb[0], XT, n, n, n, R32, nullptr, nullptr, (float*)d_out);
        stein_gemm_nt2<64><<<gs, blk, 0, stream>>>(oFin, oFin, oFin, oFin, oFin);
    }
}

// Round 11
// 459.612 us; speedup vs baseline: 1.1495x; 1.1495x over previous
//
#include <hip/hip_runtime.h>
#include <hip/hip_bf16.h>
#include <stdint.h>

typedef __attribute__((ext_vector_type(4))) float f32x4;
typedef __attribute__((ext_vector_type(8))) short s16x8;
typedef unsigned short u16;
typedef unsigned int u32;

#define BM 128
#define BK 64

// round-to-nearest-even f32 -> bf16 (bit pattern)
__device__ __forceinline__ u16 f32_to_bf16(float f) {
    uint32_t u = __float_as_uint(f);
    u = u + 0x7FFFu + ((u >> 16) & 1u);
    return (u16)(u >> 16);
}

__device__ __forceinline__ void gld_lds16(const void* g, void* l) {
    __builtin_amdgcn_global_load_lds(
        (const __attribute__((address_space(1))) uint32_t*)g,
        (__attribute__((address_space(3))) uint32_t*)l,
        16, 0, 0);
}

// Prep fusion: one read of the fp32 input produces BOTH the straight
// bf16 form and the transposed bf16 form.
__global__ void stein_prep_sq(const float* __restrict__ in, u16* __restrict__ outB,
                              u16* __restrict__ outT, int N2) {
    __shared__ float tile[32][33];
    const int tx = threadIdx.x, ty = threadIdx.y;     // 32 x 8
    const int c0 = blockIdx.x * 32, r0 = blockIdx.y * 32;
#pragma unroll
    for (int i = 0; i < 32; i += 8) {
        float v = in[(size_t)(r0 + ty + i) * N2 + (c0 + tx)];
        outB[(size_t)(r0 + ty + i) * N2 + (c0 + tx)] = f32_to_bf16(v);
        tile[ty + i][tx] = v;
    }
    __syncthreads();
#pragma unroll
    for (int i = 0; i < 32; i += 8)
        outT[(size_t)(c0 + ty + i) * N2 + (r0 + tx)] = f32_to_bf16(tile[tx][ty + i]);
}

// Rect prep: in is R x C; outB = straight bf16 (R x C); outT = transpose
// (C x R) with row stride ldoT (left half of the K-concat buffers).
__global__ void stein_prep_rect(const float* __restrict__ in, u16* __restrict__ outB,
                                u16* __restrict__ outT, int R, int C, int ldoT) {
    __shared__ float tile[32][33];
    const int tx = threadIdx.x, ty = threadIdx.y;     // 32 x 8
    const int c0 = blockIdx.x * 32, r0 = blockIdx.y * 32;
#pragma unroll
    for (int i = 0; i < 32; i += 8) {
        float v = in[(size_t)(r0 + ty + i) * C + (c0 + tx)];
        outB[(size_t)(r0 + ty + i) * C + (c0 + tx)] = f32_to_bf16(v);
        tile[ty + i][tx] = v;
    }
    __syncthreads();
#pragma unroll
    for (int i = 0; i < 32; i += 8)
        outT[(size_t)(c0 + ty + i) * ldoT + (r0 + tx)] = f32_to_bf16(tile[tx][ty + i]);
}

// Runtime-descriptor GEMM op: C[m,n] = sum_k U[m,k] V[n,k]  (NT, bf16 in).
struct GemmOp {
    const u16* U; const u16* V;
    const float* Add;
    u16* OutB; u16* OutT; float* OutF;
    int K, ldu, ldv, N, ldo;
};

// R23 multi-op kernel: 128x128x64 tile, 512 threads / 8 waves (2M x 4N,
// wave-tile 64x32), 64 KB LDS -> 2 blocks/CU = 16 waves/CU = 4 waves/SIMD.
// R22 lesson: occupancy must rise WITHOUT shrinking the tile (BNT=64 at
// 3 blocks/CU lost more FLOP/byte than it gained). R20 wall analysis: wall
// ~4360 cyc/tile-pair vs LDS-pipe floor ~1664 -> latency-gap dominated;
// doubling resident waves (m114 overlap) is the one lever that has worked.
// Cost accepted: waves 0-3 duplicate A-frag reads (+50% LDS read traffic).
// Per-acc K-accumulation order identical to R20 -> bitwise same outputs.
// XCD chunking (square ops), OutT LDS bounce, A/B bank swizzle unchanged:
// phys chunk p of row r holds logical p ^ (r&7); readers (s*4+(lane>>4))
// ^ (lane&7).
__global__ __launch_bounds__(512, 4) void stein_gemm_w8(GemmOp op0, GemmOp op1,
                                                        GemmOp op2, GemmOp op3,
                                                        GemmOp op4) {
    const int z = blockIdx.z;
    const GemmOp op = (z == 0) ? op0 : (z == 1) ? op1 : (z == 2) ? op2
                      : (z == 3) ? op3 : op4;
    int bm = blockIdx.x, bn = blockIdx.y;
    if (op.N >= 2048) {                       // square op: XCD chunking
        const int orig = (int)blockIdx.x + ((int)blockIdx.y << 4);
        const int xcd = orig & 7, idx = orig >> 3;
        bm = (xcd & 3) * 4 + (idx & 3);
        bn = (xcd >> 2) * 8 + (idx >> 2);
    }
    if (bn * 128 >= op.N) return;             // rectangular (N=512) ops

    __shared__ alignas(16) short SMEM[32768];      // 64 KB: Us[2] | Vs[2]
    short* Us0 = SMEM;                             // 2 x BM*BK
    short* Vs0 = SMEM + 2 * BM * BK;               // 2 x 128*BK

    const int t = threadIdx.x;
    const int wave = t >> 6;                  // 0..7
    const int lane = t & 63;
    const int wm = (wave >> 2) * 64;          // 2 M-groups of 64 rows
    const int wn = (wave & 3) * 32;           // 4 N-groups of 32 cols

    // staging: wave w covers A rows [16w,16w+16) and B rows [16w,16w+16);
    // 2 DMA ops each (8 rows x 128 B per op).
    const int lrow8 = lane >> 3;                  // 0..7
    const int lchunk = (lane & 7) ^ lrow8;        // swizzled source chunk
    const u16* gU = op.U + (size_t)(bm * BM + 16 * wave + lrow8) * op.ldu + lchunk * 8;
    const u16* gV = op.V + (size_t)(bn * 128 + 16 * wave + lrow8) * op.ldv + lchunk * 8;
    short* sU = Us0 + (16 * wave) * BK;
    short* sV = Vs0 + (16 * wave) * BK;
    const int bufU = BM * BK;                     // elements per buffer
    const int bufV = 128 * BK;

    f32x4 acc[4][2];
#pragma unroll
    for (int i = 0; i < 4; ++i)
#pragma unroll
        for (int j = 0; j < 2; ++j) acc[i][j] = (f32x4){0.f, 0.f, 0.f, 0.f};

    const int arow = wm + (lane & 15);
    const int brow = wn + (lane & 15);

    // prologue: stage tile 0 into buffer 0
#pragma unroll
    for (int j = 0; j < 2; ++j) {
        gld_lds16(gU + (size_t)(8 * j) * op.ldu, sU + j * 512);
        gld_lds16(gV + (size_t)(8 * j) * op.ldv, sV + j * 512);
    }

    int buf = 0;
    for (int kk = 0; kk < op.K; kk += BK) {
        __syncthreads();   // buffer `buf` staged; prior reads of buf^1 done
        if (kk + BK < op.K) {
            const int kn = kk + BK;
            const int bo = buf ^ 1;
#pragma unroll
            for (int j = 0; j < 2; ++j) {
                gld_lds16(gU + (size_t)(8 * j) * op.ldu + kn, sU + bo * bufU + j * 512);
                gld_lds16(gV + (size_t)(8 * j) * op.ldv + kn, sV + bo * bufV + j * 512);
            }
        }
#pragma unroll
        for (int s = 0; s < 2; ++s) {
            const int cx = (s * 4 + (lane >> 4)) ^ (lane & 7);   // phys chunk
            s16x8 af[4], bfr[2];
#pragma unroll
            for (int i = 0; i < 4; ++i)
                af[i] = ((const s16x8*)(Us0 + (size_t)buf * bufU))[(arow + i * 16) * (BK / 8) + cx];
#pragma unroll
            for (int j = 0; j < 2; ++j)
                bfr[j] = ((const s16x8*)(Vs0 + (size_t)buf * bufV))[(brow + j * 16) * (BK / 8) + cx];
#pragma unroll
            for (int i = 0; i < 4; ++i)
#pragma unroll
                for (int j = 0; j < 2; ++j)
                    acc[i][j] = __builtin_amdgcn_mfma_f32_16x16x32_bf16(
                        af[i], bfr[j], acc[i][j], 0, 0, 0);
        }
        buf ^= 1;
    }

    // ---- epilogue ----  C/D layout: col=lane&15, row=(lane>>4)*4+r
    const int ldo = op.ldo;
    const int ccol = lane & 15;
    const int crow = (lane >> 4) * 4;

    if (op.OutB || op.OutF) {
#pragma unroll
        for (int i = 0; i < 4; ++i) {
#pragma unroll
            for (int j = 0; j < 2; ++j) {
                const int gr0 = bm * BM + wm + i * 16 + crow;
                const int gc = bn * 128 + wn + j * 16 + ccol;
                float v[4];
#pragma unroll
                for (int r = 0; r < 4; ++r) {
                    v[r] = acc[i][j][r];
                    if (op.Add) v[r] += op.Add[(size_t)(gr0 + r) * ldo + gc];
                }
                if (op.OutB) {
#pragma unroll
                    for (int r = 0; r < 4; ++r)
                        op.OutB[(size_t)(gr0 + r) * ldo + gc] = f32_to_bf16(v[r]);
                }
                if (op.OutF) {
#pragma unroll
                    for (int r = 0; r < 4; ++r)
                        op.OutF[(size_t)(gr0 + r) * ldo + gc] = v[r];
                }
            }
        }
    }

    // transposed bf16 via LDS bounce; T[col][row], stride 132 u16.
    if (op.OutT) {
        __syncthreads();                   // all K-loop LDS reads complete
        u16* T = (u16*)SMEM;               // 128*132*2 = 33792 B <= 64 KB
#pragma unroll
        for (int i = 0; i < 4; ++i) {
#pragma unroll
            for (int j = 0; j < 2; ++j) {
                const int c_ = wn + j * 16 + ccol;
                const int r_ = wm + i * 16 + crow;      // multiple of 4
                uint2 w;
                w.x = (u32)f32_to_bf16(acc[i][j][0]) | ((u32)f32_to_bf16(acc[i][j][1]) << 16);
                w.y = (u32)f32_to_bf16(acc[i][j][2]) | ((u32)f32_to_bf16(acc[i][j][3]) << 16);
                *(uint2*)&T[c_ * 132 + r_] = w;
            }
        }
        __syncthreads();
        const int cpart = t >> 4;          // 0..31: column within pass
        const int m = t & 15;              // 16 B chunk along the row
#pragma unroll
        for (int k2 = 0; k2 < 4; ++k2) {
            const int c_ = k2 * 32 + cpart;
            uint2 x = *(const uint2*)&T[c_ * 132 + m * 8];
            uint2 y = *(const uint2*)&T[c_ * 132 + m * 8 + 4];
            uint4 w; w.x = x.x; w.y = x.y; w.z = y.x; w.w = y.y;
            *(uint4*)&op.OutT[(size_t)(bn * 128 + c_) * ldo + bm * BM + m * 8] = w;
        }
    }
}

// R20's proven single-op kernel: 256 threads, BNT=64 (LDS 48 KB -> 2-3
// blocks/CU on 512-block grids). Used for d0b / level-4 XT / Fin.
__global__ __launch_bounds__(256, 2) void stein_gemm_sm(GemmOp op0) {
    const GemmOp op = op0;
    int bm = blockIdx.x, bn = blockIdx.y;
    if (op.N >= 1024) {                       // XCD chunking (grid 16x32)
        const int orig = (int)blockIdx.x + ((int)blockIdx.y << 4);
        const int xcd = orig & 7, idx = orig >> 3;
        bm = (xcd & 3) * 4 + (idx & 3);
        bn = (xcd >> 2) * 16 + (idx >> 2);
    }
    if (bn * 64 >= op.N) return;

    __shared__ alignas(16) short SMEM[2 * BM * BK + 2 * 64 * BK];
    short* Us0 = SMEM;
    short* Vs0 = SMEM + 2 * BM * BK;

    const int t = threadIdx.x;
    const int wave = t >> 6;
    const int lane = t & 63;
    const int wm = (wave >> 1) * 64;
    const int wn = (wave & 1) * 32;

    const int lrow8 = lane >> 3;
    const int lchunk = (lane & 7) ^ lrow8;
    const u16* gU = op.U + (size_t)(bm * BM + wave * 32 + lrow8) * op.ldu + lchunk * 8;
    const u16* gV = op.V + (size_t)(bn * 64 + wave * 16 + lrow8) * op.ldv + lchunk * 8;
    short* sU = Us0 + (wave * 32) * BK;
    short* sV = Vs0 + (wave * 16) * BK;
    const int bufU = BM * BK;
    const int bufV = 64 * BK;

    f32x4 acc[4][2];
#pragma unroll
    for (int i = 0; i < 4; ++i)
#pragma unroll
        for (int j = 0; j < 2; ++j) acc[i][j] = (f32x4){0.f, 0.f, 0.f, 0.f};

    const int arow = wm + (lane & 15);
    const int brow = wn + (lane & 15);

#pragma unroll
    for (int j = 0; j < 4; ++j)
        gld_lds16(gU + (size_t)(8 * j) * op.ldu, sU + j * 512);
#pragma unroll
    for (int j = 0; j < 2; ++j)
        gld_lds16(gV + (size_t)(8 * j) * op.ldv, sV + j * 512);

    int buf = 0;
    for (int kk = 0; kk < op.K; kk += BK) {
        __syncthreads();
        if (kk + BK < op.K) {
            const int kn = kk + BK;
            const int bo = buf ^ 1;
#pragma unroll
            for (int j = 0; j < 4; ++j)
                gld_lds16(gU + (size_t)(8 * j) * op.ldu + kn, sU + bo * bufU + j * 512);
#pragma unroll
            for (int j = 0; j < 2; ++j)
                gld_lds16(gV + (size_t)(8 * j) * op.ldv + kn, sV + bo * bufV + j * 512);
        }
#pragma unroll
        for (int s = 0; s < 2; ++s) {
            const int cx = (s * 4 + (lane >> 4)) ^ (lane & 7);
            s16x8 af[4], bfr[2];
#pragma unroll
            for (int i = 0; i < 4; ++i)
                af[i] = ((const s16x8*)(Us0 + (size_t)buf * bufU))[(arow + i * 16) * (BK / 8) + cx];
#pragma unroll
            for (int j = 0; j < 2; ++j)
                bfr[j] = ((const s16x8*)(Vs0 + (size_t)buf * bufV))[(brow + j * 16) * (BK / 8) + cx];
#pragma unroll
            for (int i = 0; i < 4; ++i)
#pragma unroll
                for (int j = 0; j < 2; ++j)
                    acc[i][j] = __builtin_amdgcn_mfma_f32_16x16x32_bf16(
                        af[i], bfr[j], acc[i][j], 0, 0, 0);
        }
        buf ^= 1;
    }

    const int ldo = op.ldo;
    const int ccol = lane & 15;
    const int crow = (lane >> 4) * 4;

    if (op.OutB || op.OutF) {
#pragma unroll
        for (int i = 0; i < 4; ++i) {
#pragma unroll
            for (int j = 0; j < 2; ++j) {
                const int gr0 = bm * BM + wm + i * 16 + crow;
                const int gc = bn * 64 + wn + j * 16 + ccol;
                float v[4];
#pragma unroll
                for (int r = 0; r < 4; ++r) {
                    v[r] = acc[i][j][r];
                    if (op.Add) v[r] += op.Add[(size_t)(gr0 + r) * ldo + gc];
                }
                if (op.OutB) {
#pragma unroll
                    for (int r = 0; r < 4; ++r)
                        op.OutB[(size_t)(gr0 + r) * ldo + gc] = f32_to_bf16(v[r]);
                }
                if (op.OutF) {
#pragma unroll
                    for (int r = 0; r < 4; ++r)
                        op.OutF[(size_t)(gr0 + r) * ldo + gc] = v[r];
                }
            }
        }
    }

    if (op.OutT) {
        __syncthreads();
        u16* T = (u16*)SMEM;               // 64*132*2 = 16896 B
#pragma unroll
        for (int i = 0; i < 4; ++i) {
#pragma unroll
            for (int j = 0; j < 2; ++j) {
                const int c_ = wn + j * 16 + ccol;
                const int r_ = wm + i * 16 + crow;
                uint2 w;
                w.x = (u32)f32_to_bf16(acc[i][j][0]) | ((u32)f32_to_bf16(acc[i][j][1]) << 16);
                w.y = (u32)f32_to_bf16(acc[i][j][2]) | ((u32)f32_to_bf16(acc[i][j][3]) << 16);
                *(uint2*)&T[c_ * 132 + r_] = w;
            }
        }
        __syncthreads();
        const int cpart = t >> 4;          // 0..15
        const int m = t & 15;
#pragma unroll
        for (int k2 = 0; k2 < 4; ++k2) {
            const int c_ = k2 * 16 + cpart;
            uint2 x = *(const uint2*)&T[c_ * 132 + m * 8];
            uint2 y = *(const uint2*)&T[c_ * 132 + m * 8 + 4];
            uint4 w; w.x = x.x; w.y = x.y; w.z = y.x; w.w = y.y;
            *(uint4*)&op.OutT[(size_t)(bn * 64 + c_) * ldo + bm * BM + m * 8] = w;
        }
    }
}

static inline GemmOp mkop(const u16* U, const u16* V, int K, int ldu, int ldv,
                          const float* Add, u16* OutB, u16* OutT, float* OutF,
                          int N = 2048, int ldo = 2048) {
    GemmOp o;
    o.U = U; o.V = V; o.Add = Add; o.OutB = OutB; o.OutT = OutT; o.OutF = OutF;
    o.K = K; o.ldu = ldu; o.ldv = ldv; o.N = N; o.ldo = ldo;
    return o;
}

extern "C" void kernel_launch(void* const* d_in, const int* in_sizes, int n_in,
                              void* d_out, int out_size, void* d_ws, size_t ws_size,
                              hipStream_t stream) {
    const float* A = (const float*)d_in[0];     // (2048, 2048)
    const float* A_F = (const float*)d_in[1];   // (2048, 2048)
    const float* C = (const float*)d_in[2];     // (512, 2048)
    const float* C_F = (const float*)d_in[3];   // (512, 2048)
    const int n = 2048, p = 512;
    (void)in_sizes; (void)n_in; (void)out_size; (void)ws_size;

    char* ws = (char*)d_ws;
    const size_t MB = 1u << 20;
    // ---- Smith squaring, 5 levels -> S_32 (tail bound: see R12 notes;
    // absmax 0.5 measured, threshold 2.33).
    // d0b-fold: R_1 = [CFT|W1] [CT|Y]^T in ONE K=1024 GEMM.
    // XT computed transpose-free via operand swap:
    //   (R A)^T = NT-GEMM(U = A^T, V = R)  -> plain OutB store.
    // Asq swapped to (U=A^T, V=A) so d1's two z's share the U stream.
    u16* AT   = (u16*)(ws + 0 * MB);    // A^T  bf16  (A_0 transposed form)
    u16* Ab   = (u16*)(ws + 8 * MB);    // A    bf16  (A_0 row form)
    u16* AFT  = (u16*)(ws + 16 * MB);   // B=A_F^T row bf16 (B_0 row form)
    u16* AFb  = (u16*)(ws + 24 * MB);   // A_F  bf16  (B_0 transposed form)
    u16* WYU  = (u16*)(ws + 32 * MB);   // 2048x1024: [CFT | W1=B C_F^T]
    u16* WYV  = (u16*)(ws + 36 * MB);   // 2048x1024: [CT  | Y=A^T C^T]
    u16* XT   = (u16*)(ws + 32 * MB);   // (R A_i)^T — overlaps WYU/WYV (dead after d0b)
    float* R32 = (float*)(ws + 40 * MB);// running R fp32
    u16* Rb   = (u16*)(ws + 56 * MB);   // running R bf16 row
    u16* CFb  = (u16*)(ws + 64 * MB);   // C_F bf16 row (level 0 only)
    u16* Cb   = (u16*)(ws + 66 * MB);   // C   bf16 row (level 0 only)
    u16* Tb1  = (u16*)(ws + 68 * MB);   // ping-pong set 1: B_i row
    u16* TbT1 = (u16*)(ws + 76 * MB);   //                  B_i^T
    u16* Ub1  = (u16*)(ws + 84 * MB);   //                  A_i row
    u16* UbT1 = (u16*)(ws + 92 * MB);   //                  A_i^T   (top = 100 MB)

    dim3 tb(32, 8);
    stein_prep_sq<<<dim3(64, 64), tb, 0, stream>>>(A, Ab, AT, n);
    stein_prep_sq<<<dim3(64, 64), tb, 0, stream>>>(A_F, AFb, AFT, n);
    stein_prep_rect<<<dim3(64, 16), tb, 0, stream>>>(C_F, CFb, WYU, p, n, 2 * p);
    stein_prep_rect<<<dim3(64, 16), tb, 0, stream>>>(C, Cb, WYV, p, n, 2 * p);

    u16* Tb[2]  = {AFT, Tb1};
    u16* TbT[2] = {AFb, TbT1};
    u16* Ub[2]  = {Ab, Ub1};
    u16* UbT[2] = {AT, UbT1};

    dim3 blk8(512), blk(256);
    dim3 g2(16, 16, 2), g4(16, 16, 4);
    dim3 gs(16, 32, 1);                 // sm kernel single-op grid

    // d0 (z=4): level-0 independent ops. Long K=2048 small-N ops at LOW z
    // (dispatched first) so stragglers are short.
    {
        GemmOp oW1  = mkop(AFT, CFb, n, n, n, nullptr, WYU + p, nullptr, nullptr, p, 2 * p);
        GemmOp oY   = mkop(AT, Cb, n, n, n, nullptr, WYV + p, nullptr, nullptr, p, 2 * p);
        GemmOp oAsq = mkop(AT, Ab, n, n, n, nullptr, UbT1, Ub1, nullptr);   // swapped
        GemmOp oBsq = mkop(AFT, AFb, n, n, n, nullptr, Tb1, TbT1, nullptr);
        stein_gemm_w8<<<g4, blk8, 0, stream>>>(oW1, oY, oAsq, oBsq, oBsq);
    }
    // d0b: R_1 = [CFT|W1] [CT|Y]^T  (K=1024 concat = RHS + B RHS A)
    {
        GemmOp oR1 = mkop(WYU, WYV, 2 * p, 2 * p, 2 * p, nullptr, Rb, nullptr, R32);
        stein_gemm_sm<<<gs, blk, 0, stream>>>(oR1);
    }

    // levels 1..3: full doubling, stream-sharing pairing.
    // R_j = S_{2^j}; after level 3: R_4 = S_16, A_4 = A^16 in set 0.
    // Level 3 drops dead outputs (level 4 needs only UbT[0] and Tb[0]).
    for (int i = 1; i < 4; ++i) {
        const int c = i & 1, nx = c ^ 1;
        // d1: {XT = (R A_i)^T via swap, Asq swapped} — shared U = A_i^T.
        GemmOp oXT = mkop(UbT[c], Rb, n, n, n, nullptr, XT, nullptr, nullptr);
        GemmOp oAsq = mkop(UbT[c], Ub[c], n, n, n, nullptr, UbT[nx],
                           (i == 3) ? nullptr : Ub[nx], nullptr);
        stein_gemm_w8<<<g2, blk8, 0, stream>>>(oXT, oAsq, oAsq, oAsq, oAsq);
        // d2: {Rup = B_i X + R, Bsq = B_i^2} — shared U stream = B_i.
        GemmOp oRup = mkop(Tb[c], XT, n, n, n, R32, Rb, nullptr, R32);
        GemmOp oBsq = mkop(Tb[c], TbT[c], n, n, n, nullptr, Tb[nx],
                           (i == 3) ? nullptr : TbT[nx], nullptr);
        stein_gemm_w8<<<g2, blk8, 0, stream>>>(oRup, oBsq, oBsq, oBsq, oBsq);
    }

    // level 4 (final): S_32 = R_4 + B_4 (R_4 A_4) -> d_out. A_4/B_4 in set 0.
    {
        GemmOp oXT = mkop(UbT[0], Rb, n, n, n, nullptr, XT, nullptr, nullptr);
        stein_gemm_sm<<<gs, blk, 0, stream>>>(oXT);
        GemmOp oFin = mkop(Tb[0], XT, n, n, n, R32, nullptr, nullptr, (float*)d_out);
        stein_gemm_sm<<<gs, blk, 0, stream>>>(oFin);
    }
}

// Round 12
// 437.722 us; speedup vs baseline: 1.2069x; 1.0500x over previous
//
#include <hip/hip_runtime.h>
#include <hip/hip_bf16.h>
#include <stdint.h>

typedef __attribute__((ext_vector_type(4))) float f32x4;
typedef __attribute__((ext_vector_type(8))) short s16x8;
typedef unsigned short u16;
typedef unsigned int u32;

#define BM 128
#define BK 64

// round-to-nearest-even f32 -> bf16 (bit pattern)
__device__ __forceinline__ u16 f32_to_bf16(float f) {
    uint32_t u = __float_as_uint(f);
    u = u + 0x7FFFu + ((u >> 16) & 1u);
    return (u16)(u >> 16);
}

__device__ __forceinline__ float bf16_to_f32(u16 h) {
    return __uint_as_float((u32)h << 16);
}

__device__ __forceinline__ void gld_lds16(const void* g, void* l) {
    __builtin_amdgcn_global_load_lds(
        (const __attribute__((address_space(1))) uint32_t*)g,
        (__attribute__((address_space(3))) uint32_t*)l,
        16, 0, 0);
}

// Prep fusion: one read of the fp32 input produces BOTH the straight
// bf16 form and the transposed bf16 form.
__global__ void stein_prep_sq(const float* __restrict__ in, u16* __restrict__ outB,
                              u16* __restrict__ outT, int N2) {
    __shared__ float tile[32][33];
    const int tx = threadIdx.x, ty = threadIdx.y;     // 32 x 8
    const int c0 = blockIdx.x * 32, r0 = blockIdx.y * 32;
#pragma unroll
    for (int i = 0; i < 32; i += 8) {
        float v = in[(size_t)(r0 + ty + i) * N2 + (c0 + tx)];
        outB[(size_t)(r0 + ty + i) * N2 + (c0 + tx)] = f32_to_bf16(v);
        tile[ty + i][tx] = v;
    }
    __syncthreads();
#pragma unroll
    for (int i = 0; i < 32; i += 8)
        outT[(size_t)(c0 + ty + i) * N2 + (r0 + tx)] = f32_to_bf16(tile[tx][ty + i]);
}

// Rect prep: in is R x C; outB = straight bf16 (R x C); outT = transpose
// (C x R) with row stride ldoT (left half of the K-concat buffers).
__global__ void stein_prep_rect(const float* __restrict__ in, u16* __restrict__ outB,
                                u16* __restrict__ outT, int R, int C, int ldoT) {
    __shared__ float tile[32][33];
    const int tx = threadIdx.x, ty = threadIdx.y;     // 32 x 8
    const int c0 = blockIdx.x * 32, r0 = blockIdx.y * 32;
#pragma unroll
    for (int i = 0; i < 32; i += 8) {
        float v = in[(size_t)(r0 + ty + i) * C + (c0 + tx)];
        outB[(size_t)(r0 + ty + i) * C + (c0 + tx)] = f32_to_bf16(v);
        tile[ty + i][tx] = v;
    }
    __syncthreads();
#pragma unroll
    for (int i = 0; i < 32; i += 8)
        outT[(size_t)(c0 + ty + i) * ldoT + (r0 + tx)] = f32_to_bf16(tile[tx][ty + i]);
}

// Runtime-descriptor GEMM op: C[m,n] = sum_k U[m,k] V[n,k]  (NT, bf16 in).
// R24: Add is now bf16 (the fp32 R-chain is dropped — the product term
// already passed through bf16 every level via Rb, so fp32 only protected
// the additive chain; one extra bf16 rounding/level costs ~0.1 absmax vs
// a 2.33 threshold, and saves ~100 MB of serial-chain traffic).
struct GemmOp {
    const u16* U; const u16* V;
    const u16* Add;                        // bf16 elementwise add (or null)
    u16* OutB; u16* OutT; float* OutF;
    int K, ldu, ldv, N, ldo;
};

// R23 multi-op kernel: 128x128x64 tile, 512 threads / 8 waves (2M x 4N,
// wave-tile 64x32), 64 KB LDS -> 2 blocks/CU = 16 waves/CU = 4 waves/SIMD.
// (R22: occupancy must rise WITHOUT shrinking the tile; R14: triple-buffer
// costs a block/CU and loses; block supply caps residency at 2/CU.)
// Per-acc K-accumulation order unchanged across rounds.
// XCD chunking (square ops), OutT LDS bounce, A/B bank swizzle: phys chunk
// p of row r holds logical p ^ (r&7); readers (s*4+(lane>>4)) ^ (lane&7).
__global__ __launch_bounds__(512, 4) void stein_gemm_w8(GemmOp op0, GemmOp op1,
                                                        GemmOp op2, GemmOp op3,
                                                        GemmOp op4) {
    const int z = blockIdx.z;
    const GemmOp op = (z == 0) ? op0 : (z == 1) ? op1 : (z == 2) ? op2
                      : (z == 3) ? op3 : op4;
    int bm = blockIdx.x, bn = blockIdx.y;
    if (op.N >= 2048) {                       // square op: XCD chunking
        const int orig = (int)blockIdx.x + ((int)blockIdx.y << 4);
        const int xcd = orig & 7, idx = orig >> 3;
        bm = (xcd & 3) * 4 + (idx & 3);
        bn = (xcd >> 2) * 8 + (idx >> 2);
    }
    if (bn * 128 >= op.N) return;             // rectangular (N=512) ops

    __shared__ alignas(16) short SMEM[32768];      // 64 KB: Us[2] | Vs[2]
    short* Us0 = SMEM;                             // 2 x BM*BK
    short* Vs0 = SMEM + 2 * BM * BK;               // 2 x 128*BK

    const int t = threadIdx.x;
    const int wave = t >> 6;                  // 0..7
    const int lane = t & 63;
    const int wm = (wave >> 2) * 64;          // 2 M-groups of 64 rows
    const int wn = (wave & 3) * 32;           // 4 N-groups of 32 cols

    // staging: wave w covers A rows [16w,16w+16) and B rows [16w,16w+16);
    // 2 DMA ops each (8 rows x 128 B per op).
    const int lrow8 = lane >> 3;                  // 0..7
    const int lchunk = (lane & 7) ^ lrow8;        // swizzled source chunk
    const u16* gU = op.U + (size_t)(bm * BM + 16 * wave + lrow8) * op.ldu + lchunk * 8;
    const u16* gV = op.V + (size_t)(bn * 128 + 16 * wave + lrow8) * op.ldv + lchunk * 8;
    short* sU = Us0 + (16 * wave) * BK;
    short* sV = Vs0 + (16 * wave) * BK;
    const int bufU = BM * BK;                     // elements per buffer
    const int bufV = 128 * BK;

    f32x4 acc[4][2];
#pragma unroll
    for (int i = 0; i < 4; ++i)
#pragma unroll
        for (int j = 0; j < 2; ++j) acc[i][j] = (f32x4){0.f, 0.f, 0.f, 0.f};

    const int arow = wm + (lane & 15);
    const int brow = wn + (lane & 15);

    // prologue: stage tile 0 into buffer 0
#pragma unroll
    for (int j = 0; j < 2; ++j) {
        gld_lds16(gU + (size_t)(8 * j) * op.ldu, sU + j * 512);
        gld_lds16(gV + (size_t)(8 * j) * op.ldv, sV + j * 512);
    }

    int buf = 0;
    for (int kk = 0; kk < op.K; kk += BK) {
        __syncthreads();   // buffer `buf` staged; prior reads of buf^1 done
        if (kk + BK < op.K) {
            const int kn = kk + BK;
            const int bo = buf ^ 1;
#pragma unroll
            for (int j = 0; j < 2; ++j) {
                gld_lds16(gU + (size_t)(8 * j) * op.ldu + kn, sU + bo * bufU + j * 512);
                gld_lds16(gV + (size_t)(8 * j) * op.ldv + kn, sV + bo * bufV + j * 512);
            }
        }
#pragma unroll
        for (int s = 0; s < 2; ++s) {
            const int cx = (s * 4 + (lane >> 4)) ^ (lane & 7);   // phys chunk
            s16x8 af[4], bfr[2];
#pragma unroll
            for (int i = 0; i < 4; ++i)
                af[i] = ((const s16x8*)(Us0 + (size_t)buf * bufU))[(arow + i * 16) * (BK / 8) + cx];
#pragma unroll
            for (int j = 0; j < 2; ++j)
                bfr[j] = ((const s16x8*)(Vs0 + (size_t)buf * bufV))[(brow + j * 16) * (BK / 8) + cx];
#pragma unroll
            for (int i = 0; i < 4; ++i)
#pragma unroll
                for (int j = 0; j < 2; ++j)
                    acc[i][j] = __builtin_amdgcn_mfma_f32_16x16x32_bf16(
                        af[i], bfr[j], acc[i][j], 0, 0, 0);
        }
        buf ^= 1;
    }

    // ---- epilogue ----  C/D layout: col=lane&15, row=(lane>>4)*4+r
    const int ldo = op.ldo;
    const int ccol = lane & 15;
    const int crow = (lane >> 4) * 4;

    if (op.OutB || op.OutF) {
#pragma unroll
        for (int i = 0; i < 4; ++i) {
#pragma unroll
            for (int j = 0; j < 2; ++j) {
                const int gr0 = bm * BM + wm + i * 16 + crow;
                const int gc = bn * 128 + wn + j * 16 + ccol;
                float v[4];
#pragma unroll
                for (int r = 0; r < 4; ++r) {
                    v[r] = acc[i][j][r];
                    if (op.Add) v[r] += bf16_to_f32(op.Add[(size_t)(gr0 + r) * ldo + gc]);
                }
                if (op.OutB) {
#pragma unroll
                    for (int r = 0; r < 4; ++r)
                        op.OutB[(size_t)(gr0 + r) * ldo + gc] = f32_to_bf16(v[r]);
                }
                if (op.OutF) {
#pragma unroll
                    for (int r = 0; r < 4; ++r)
                        op.OutF[(size_t)(gr0 + r) * ldo + gc] = v[r];
                }
            }
        }
    }

    // transposed bf16 via LDS bounce; T[col][row], stride 132 u16.
    if (op.OutT) {
        __syncthreads();                   // all K-loop LDS reads complete
        u16* T = (u16*)SMEM;               // 128*132*2 = 33792 B <= 64 KB
#pragma unroll
        for (int i = 0; i < 4; ++i) {
#pragma unroll
            for (int j = 0; j < 2; ++j) {
                const int c_ = wn + j * 16 + ccol;
                const int r_ = wm + i * 16 + crow;      // multiple of 4
                uint2 w;
                w.x = (u32)f32_to_bf16(acc[i][j][0]) | ((u32)f32_to_bf16(acc[i][j][1]) << 16);
                w.y = (u32)f32_to_bf16(acc[i][j][2]) | ((u32)f32_to_bf16(acc[i][j][3]) << 16);
                *(uint2*)&T[c_ * 132 + r_] = w;
            }
        }
        __syncthreads();
        const int cpart = t >> 4;          // 0..31: column within pass
        const int m = t & 15;              // 16 B chunk along the row
#pragma unroll
        for (int k2 = 0; k2 < 4; ++k2) {
            const int c_ = k2 * 32 + cpart;
            uint2 x = *(const uint2*)&T[c_ * 132 + m * 8];
            uint2 y = *(const uint2*)&T[c_ * 132 + m * 8 + 4];
            uint4 w; w.x = x.x; w.y = x.y; w.z = y.x; w.w = y.y;
            *(uint4*)&op.OutT[(size_t)(bn * 128 + c_) * ldo + bm * BM + m * 8] = w;
        }
    }
}

// Single-op kernel: 256 threads, BNT=64 (LDS 48 KB, 512-block grids ->
// 2 blocks/CU). Used for d0b / level-4 XT / Fin.
__global__ __launch_bounds__(256, 2) void stein_gemm_sm(GemmOp op0) {
    const GemmOp op = op0;
    int bm = blockIdx.x, bn = blockIdx.y;
    if (op.N >= 1024) {                       // XCD chunking (grid 16x32)
        const int orig = (int)blockIdx.x + ((int)blockIdx.y << 4);
        const int xcd = orig & 7, idx = orig >> 3;
        bm = (xcd & 3) * 4 + (idx & 3);
        bn = (xcd >> 2) * 16 + (idx >> 2);
    }
    if (bn * 64 >= op.N) return;

    __shared__ alignas(16) short SMEM[2 * BM * BK + 2 * 64 * BK];
    short* Us0 = SMEM;
    short* Vs0 = SMEM + 2 * BM * BK;

    const int t = threadIdx.x;
    const int wave = t >> 6;
    const int lane = t & 63;
    const int wm = (wave >> 1) * 64;
    const int wn = (wave & 1) * 32;

    const int lrow8 = lane >> 3;
    const int lchunk = (lane & 7) ^ lrow8;
    const u16* gU = op.U + (size_t)(bm * BM + wave * 32 + lrow8) * op.ldu + lchunk * 8;
    const u16* gV = op.V + (size_t)(bn * 64 + wave * 16 + lrow8) * op.ldv + lchunk * 8;
    short* sU = Us0 + (wave * 32) * BK;
    short* sV = Vs0 + (wave * 16) * BK;
    const int bufU = BM * BK;
    const int bufV = 64 * BK;

    f32x4 acc[4][2];
#pragma unroll
    for (int i = 0; i < 4; ++i)
#pragma unroll
        for (int j = 0; j < 2; ++j) acc[i][j] = (f32x4){0.f, 0.f, 0.f, 0.f};

    const int arow = wm + (lane & 15);
    const int brow = wn + (lane & 15);

#pragma unroll
    for (int j = 0; j < 4; ++j)
        gld_lds16(gU + (size_t)(8 * j) * op.ldu, sU + j * 512);
#pragma unroll
    for (int j = 0; j < 2; ++j)
        gld_lds16(gV + (size_t)(8 * j) * op.ldv, sV + j * 512);

    int buf = 0;
    for (int kk = 0; kk < op.K; kk += BK) {
        __syncthreads();
        if (kk + BK < op.K) {
            const int kn = kk + BK;
            const int bo = buf ^ 1;
#pragma unroll
            for (int j = 0; j < 4; ++j)
                gld_lds16(gU + (size_t)(8 * j) * op.ldu + kn, sU + bo * bufU + j * 512);
#pragma unroll
            for (int j = 0; j < 2; ++j)
                gld_lds16(gV + (size_t)(8 * j) * op.ldv + kn, sV + bo * bufV + j * 512);
        }
#pragma unroll
        for (int s = 0; s < 2; ++s) {
            const int cx = (s * 4 + (lane >> 4)) ^ (lane & 7);
            s16x8 af[4], bfr[2];
#pragma unroll
            for (int i = 0; i < 4; ++i)
                af[i] = ((const s16x8*)(Us0 + (size_t)buf * bufU))[(arow + i * 16) * (BK / 8) + cx];
#pragma unroll
            for (int j = 0; j < 2; ++j)
                bfr[j] = ((const s16x8*)(Vs0 + (size_t)buf * bufV))[(brow + j * 16) * (BK / 8) + cx];
#pragma unroll
            for (int i = 0; i < 4; ++i)
#pragma unroll
                for (int j = 0; j < 2; ++j)
                    acc[i][j] = __builtin_amdgcn_mfma_f32_16x16x32_bf16(
                        af[i], bfr[j], acc[i][j], 0, 0, 0);
        }
        buf ^= 1;
    }

    const int ldo = op.ldo;
    const int ccol = lane & 15;
    const int crow = (lane >> 4) * 4;

    if (op.OutB || op.OutF) {
#pragma unroll
        for (int i = 0; i < 4; ++i) {
#pragma unroll
            for (int j = 0; j < 2; ++j) {
                const int gr0 = bm * BM + wm + i * 16 + crow;
                const int gc = bn * 64 + wn + j * 16 + ccol;
                float v[4];
#pragma unroll
                for (int r = 0; r < 4; ++r) {
                    v[r] = acc[i][j][r];
                    if (op.Add) v[r] += bf16_to_f32(op.Add[(size_t)(gr0 + r) * ldo + gc]);
                }
                if (op.OutB) {
#pragma unroll
                    for (int r = 0; r < 4; ++r)
                        op.OutB[(size_t)(gr0 + r) * ldo + gc] = f32_to_bf16(v[r]);
                }
                if (op.OutF) {
#pragma unroll
                    for (int r = 0; r < 4; ++r)
                        op.OutF[(size_t)(gr0 + r) * ldo + gc] = v[r];
                }
            }
        }
    }

    if (op.OutT) {
        __syncthreads();
        u16* T = (u16*)SMEM;               // 64*132*2 = 16896 B
#pragma unroll
        for (int i = 0; i < 4; ++i) {
#pragma unroll
            for (int j = 0; j < 2; ++j) {
                const int c_ = wn + j * 16 + ccol;
                const int r_ = wm + i * 16 + crow;
                uint2 w;
                w.x = (u32)f32_to_bf16(acc[i][j][0]) | ((u32)f32_to_bf16(acc[i][j][1]) << 16);
                w.y = (u32)f32_to_bf16(acc[i][j][2]) | ((u32)f32_to_bf16(acc[i][j][3]) << 16);
                *(uint2*)&T[c_ * 132 + r_] = w;
            }
        }
        __syncthreads();
        const int cpart = t >> 4;          // 0..15
        const int m = t & 15;
#pragma unroll
        for (int k2 = 0; k2 < 4; ++k2) {
            const int c_ = k2 * 16 + cpart;
            uint2 x = *(const uint2*)&T[c_ * 132 + m * 8];
            uint2 y = *(const uint2*)&T[c_ * 132 + m * 8 + 4];
            uint4 w; w.x = x.x; w.y = x.y; w.z = y.x; w.w = y.y;
            *(uint4*)&op.OutT[(size_t)(bn * 64 + c_) * ldo + bm * BM + m * 8] = w;
        }
    }
}

static inline GemmOp mkop(const u16* U, const u16* V, int K, int ldu, int ldv,
                          const u16* Add, u16* OutB, u16* OutT, float* OutF,
                          int N = 2048, int ldo = 2048) {
    GemmOp o;
    o.U = U; o.V = V; o.Add = Add; o.OutB = OutB; o.OutT = OutT; o.OutF = OutF;
    o.K = K; o.ldu = ldu; o.ldv = ldv; o.N = N; o.ldo = ldo;
    return o;
}

extern "C" void kernel_launch(void* const* d_in, const int* in_sizes, int n_in,
                              void* d_out, int out_size, void* d_ws, size_t ws_size,
                              hipStream_t stream) {
    const float* A = (const float*)d_in[0];     // (2048, 2048)
    const float* A_F = (const float*)d_in[1];   // (2048, 2048)
    const float* C = (const float*)d_in[2];     // (512, 2048)
    const float* C_F = (const float*)d_in[3];   // (512, 2048)
    const int n = 2048, p = 512;
    (void)in_sizes; (void)n_in; (void)out_size; (void)ws_size;

    char* ws = (char*)d_ws;
    const size_t MB = 1u << 20;
    // ---- Smith squaring, 5 levels -> S_32 (tail bound: see R12 notes).
    // d0b-fold: R_1 = [CFT|W1] [CT|Y]^T in ONE K=1024 GEMM.
    // XT transpose-free via operand swap: (R A)^T = NT(U=A^T, V=R).
    // Asq swapped (U=A^T, V=A) so d1's two z's share the U stream.
    // R24: R carried in bf16 only (Rb); Rup is in-place Rb = bf16(BX+Rb)
    // (each element read+written by exactly one thread, read-before-write).
    u16* AT   = (u16*)(ws + 0 * MB);    // A^T  bf16  (A_0 transposed form)
    u16* Ab   = (u16*)(ws + 8 * MB);    // A    bf16  (A_0 row form)
    u16* AFT  = (u16*)(ws + 16 * MB);   // B=A_F^T row bf16 (B_0 row form)
    u16* AFb  = (u16*)(ws + 24 * MB);   // A_F  bf16  (B_0 transposed form)
    u16* WYU  = (u16*)(ws + 32 * MB);   // 2048x1024: [CFT | W1=B C_F^T]
    u16* WYV  = (u16*)(ws + 36 * MB);   // 2048x1024: [CT  | Y=A^T C^T]
    u16* XT   = (u16*)(ws + 32 * MB);   // (R A_i)^T — overlaps WYU/WYV (dead after d0b)
    u16* Rb   = (u16*)(ws + 56 * MB);   // running R bf16 row
    u16* CFb  = (u16*)(ws + 64 * MB);   // C_F bf16 row (level 0 only)
    u16* Cb   = (u16*)(ws + 66 * MB);   // C   bf16 row (level 0 only)
    u16* Tb1  = (u16*)(ws + 68 * MB);   // ping-pong set 1: B_i row
    u16* TbT1 = (u16*)(ws + 76 * MB);   //                  B_i^T
    u16* Ub1  = (u16*)(ws + 84 * MB);   //                  A_i row
    u16* UbT1 = (u16*)(ws + 92 * MB);   //                  A_i^T   (top = 100 MB)

    dim3 tb(32, 8);
    stein_prep_sq<<<dim3(64, 64), tb, 0, stream>>>(A, Ab, AT, n);
    stein_prep_sq<<<dim3(64, 64), tb, 0, stream>>>(A_F, AFb, AFT, n);
    stein_prep_rect<<<dim3(64, 16), tb, 0, stream>>>(C_F, CFb, WYU, p, n, 2 * p);
    stein_prep_rect<<<dim3(64, 16), tb, 0, stream>>>(C, Cb, WYV, p, n, 2 * p);

    u16* Tb[2]  = {AFT, Tb1};
    u16* TbT[2] = {AFb, TbT1};
    u16* Ub[2]  = {Ab, Ub1};
    u16* UbT[2] = {AT, UbT1};

    dim3 blk8(512), blk(256);
    dim3 g2(16, 16, 2), g4(16, 16, 4);
    dim3 gs(16, 32, 1);                 // sm kernel single-op grid

    // d0 (z=4): level-0 independent ops.
    {
        GemmOp oW1  = mkop(AFT, CFb, n, n, n, nullptr, WYU + p, nullptr, nullptr, p, 2 * p);
        GemmOp oY   = mkop(AT, Cb, n, n, n, nullptr, WYV + p, nullptr, nullptr, p, 2 * p);
        GemmOp oAsq = mkop(AT, Ab, n, n, n, nullptr, UbT1, Ub1, nullptr);   // swapped
        GemmOp oBsq = mkop(AFT, AFb, n, n, n, nullptr, Tb1, TbT1, nullptr);
        stein_gemm_w8<<<g4, blk8, 0, stream>>>(oW1, oY, oAsq, oBsq, oBsq);
    }
    // d0b: R_1 = [CFT|W1] [CT|Y]^T  (K=1024 concat = RHS + B RHS A)
    {
        GemmOp oR1 = mkop(WYU, WYV, 2 * p, 2 * p, 2 * p, nullptr, Rb, nullptr, nullptr);
        stein_gemm_sm<<<gs, blk, 0, stream>>>(oR1);
    }

    // levels 1..3: full doubling, stream-sharing pairing.
    // Level 3 drops dead outputs (level 4 needs only UbT[0] and Tb[0]).
    for (int i = 1; i < 4; ++i) {
        const int c = i & 1, nx = c ^ 1;
        // d1: {XT = (R A_i)^T via swap, Asq swapped} — shared U = A_i^T.
        GemmOp oXT = mkop(UbT[c], Rb, n, n, n, nullptr, XT, nullptr, nullptr);
        GemmOp oAsq = mkop(UbT[c], Ub[c], n, n, n, nullptr, UbT[nx],
                           (i == 3) ? nullptr : Ub[nx], nullptr);
        stein_gemm_w8<<<g2, blk8, 0, stream>>>(oXT, oAsq, oAsq, oAsq, oAsq);
        // d2: {Rup = bf16(B_i X + Rb) in place, Bsq} — shared U stream = B_i.
        GemmOp oRup = mkop(Tb[c], XT, n, n, n, Rb, Rb, nullptr, nullptr);
        GemmOp oBsq = mkop(Tb[c], TbT[c], n, n, n, nullptr, Tb[nx],
                           (i == 3) ? nullptr : TbT[nx], nullptr);
        stein_gemm_w8<<<g2, blk8, 0, stream>>>(oRup, oBsq, oBsq, oBsq, oBsq);
    }

    // level 4 (final): S_32 = Rb + B_4 (R_4 A_4) -> d_out. A_4/B_4 in set 0.
    {
        GemmOp oXT = mkop(UbT[0], Rb, n, n, n, nullptr, XT, nullptr, nullptr);
        stein_gemm_sm<<<gs, blk, 0, stream>>>(oXT);
        GemmOp oFin = mkop(Tb[0], XT, n, n, n, Rb, nullptr, nullptr, (float*)d_out);
        stein_gemm_sm<<<gs, blk, 0, stream>>>(oFin);
    }
}

// Round 13
// 433.693 us; speedup vs baseline: 1.2182x; 1.0093x over previous
//
#include <hip/hip_runtime.h>
#include <hip/hip_bf16.h>
#include <stdint.h>

typedef __attribute__((ext_vector_type(4))) float f32x4;
typedef __attribute__((ext_vector_type(8))) short s16x8;
typedef unsigned short u16;
typedef unsigned int u32;

#define BM 128
#define BK 64

// round-to-nearest-even f32 -> bf16 (bit pattern)
__device__ __forceinline__ u16 f32_to_bf16(float f) {
    uint32_t u = __float_as_uint(f);
    u = u + 0x7FFFu + ((u >> 16) & 1u);
    return (u16)(u >> 16);
}

__device__ __forceinline__ float bf16_to_f32(u16 h) {
    return __uint_as_float((u32)h << 16);
}

__device__ __forceinline__ void gld_lds16(const void* g, void* l) {
    __builtin_amdgcn_global_load_lds(
        (const __attribute__((address_space(1))) uint32_t*)g,
        (__attribute__((address_space(3))) uint32_t*)l,
        16, 0, 0);
}

// R25: all four preps fused into one z-batched kernel (sq = rect with R=C).
// in: R x C fp32; outB: R x C bf16; outT: C x R bf16, row stride ldoT.
struct PrepOp { const float* in; u16* outB; u16* outT; int R, C, ldoT; };

__global__ void stein_prep(PrepOp p0, PrepOp p1, PrepOp p2, PrepOp p3) {
    const int z = blockIdx.z;
    const PrepOp p = (z == 0) ? p0 : (z == 1) ? p1 : (z == 2) ? p2 : p3;
    const int tx = threadIdx.x, ty = threadIdx.y;     // 32 x 8
    const int c0 = blockIdx.x * 32, r0 = blockIdx.y * 32;
    if (r0 >= p.R || c0 >= p.C) return;               // rect ops exit early
    __shared__ float tile[32][33];
#pragma unroll
    for (int i = 0; i < 32; i += 8) {
        float v = p.in[(size_t)(r0 + ty + i) * p.C + (c0 + tx)];
        p.outB[(size_t)(r0 + ty + i) * p.C + (c0 + tx)] = f32_to_bf16(v);
        tile[ty + i][tx] = v;
    }
    __syncthreads();
#pragma unroll
    for (int i = 0; i < 32; i += 8)
        p.outT[(size_t)(c0 + ty + i) * p.ldoT + (r0 + tx)] = f32_to_bf16(tile[tx][ty + i]);
}

// Runtime-descriptor GEMM op: C[m,n] = sum_k U[m,k] V[n,k]  (NT, bf16 in).
// R24: Add is bf16 (fp32 R-chain dropped; ~0.1 absmax/level vs 2.33
// threshold, saves ~100 MB serial-chain traffic).
struct GemmOp {
    const u16* U; const u16* V;
    const u16* Add;                        // bf16 elementwise add (or null)
    u16* OutB; u16* OutT; float* OutF;
    int K, ldu, ldv, N, ldo;
};

// R23 multi-op kernel: 128x128x64 tile, 512 threads / 8 waves (2M x 4N,
// wave-tile 64x32), 64 KB LDS -> 2 blocks/CU = 16 waves/CU = 4 waves/SIMD.
// Structural model (R24 counters): per CU per K-tile, 192 ds_read_b128
// (~2300 cyc) vs 256 MFMA (~1240 cyc) -> MfmaUtil cap ~35%; measured 28.
// All escapes measured & lost: wider tile = supply-capped (R15), smaller
// tile = intensity loss (R22), deep pipeline (R13-R16), B-from-global (R19).
// XCD chunking (square ops), OutT LDS bounce, A/B bank swizzle: phys chunk
// p of row r holds logical p ^ (r&7); readers (s*4+(lane>>4)) ^ (lane&7).
__global__ __launch_bounds__(512, 4) void stein_gemm_w8(GemmOp op0, GemmOp op1,
                                                        GemmOp op2, GemmOp op3,
                                                        GemmOp op4) {
    const int z = blockIdx.z;
    const GemmOp op = (z == 0) ? op0 : (z == 1) ? op1 : (z == 2) ? op2
                      : (z == 3) ? op3 : op4;
    int bm = blockIdx.x, bn = blockIdx.y;
    if (op.N >= 2048) {                       // square op: XCD chunking
        const int orig = (int)blockIdx.x + ((int)blockIdx.y << 4);
        const int xcd = orig & 7, idx = orig >> 3;
        bm = (xcd & 3) * 4 + (idx & 3);
        bn = (xcd >> 2) * 8 + (idx >> 2);
    }
    if (bn * 128 >= op.N) return;             // rectangular (N=512) ops

    __shared__ alignas(16) short SMEM[32768];      // 64 KB: Us[2] | Vs[2]
    short* Us0 = SMEM;                             // 2 x BM*BK
    short* Vs0 = SMEM + 2 * BM * BK;               // 2 x 128*BK

    const int t = threadIdx.x;
    const int wave = t >> 6;                  // 0..7
    const int lane = t & 63;
    const int wm = (wave >> 2) * 64;          // 2 M-groups of 64 rows
    const int wn = (wave & 3) * 32;           // 4 N-groups of 32 cols

    // staging: wave w covers A rows [16w,16w+16) and B rows [16w,16w+16);
    // 2 DMA ops each (8 rows x 128 B per op).
    const int lrow8 = lane >> 3;                  // 0..7
    const int lchunk = (lane & 7) ^ lrow8;        // swizzled source chunk
    const u16* gU = op.U + (size_t)(bm * BM + 16 * wave + lrow8) * op.ldu + lchunk * 8;
    const u16* gV = op.V + (size_t)(bn * 128 + 16 * wave + lrow8) * op.ldv + lchunk * 8;
    short* sU = Us0 + (16 * wave) * BK;
    short* sV = Vs0 + (16 * wave) * BK;
    const int bufU = BM * BK;                     // elements per buffer
    const int bufV = 128 * BK;

    f32x4 acc[4][2];
#pragma unroll
    for (int i = 0; i < 4; ++i)
#pragma unroll
        for (int j = 0; j < 2; ++j) acc[i][j] = (f32x4){0.f, 0.f, 0.f, 0.f};

    const int arow = wm + (lane & 15);
    const int brow = wn + (lane & 15);

    // prologue: stage tile 0 into buffer 0
#pragma unroll
    for (int j = 0; j < 2; ++j) {
        gld_lds16(gU + (size_t)(8 * j) * op.ldu, sU + j * 512);
        gld_lds16(gV + (size_t)(8 * j) * op.ldv, sV + j * 512);
    }

    int buf = 0;
    for (int kk = 0; kk < op.K; kk += BK) {
        __syncthreads();   // buffer `buf` staged; prior reads of buf^1 done
        if (kk + BK < op.K) {
            const int kn = kk + BK;
            const int bo = buf ^ 1;
#pragma unroll
            for (int j = 0; j < 2; ++j) {
                gld_lds16(gU + (size_t)(8 * j) * op.ldu + kn, sU + bo * bufU + j * 512);
                gld_lds16(gV + (size_t)(8 * j) * op.ldv + kn, sV + bo * bufV + j * 512);
            }
        }
#pragma unroll
        for (int s = 0; s < 2; ++s) {
            const int cx = (s * 4 + (lane >> 4)) ^ (lane & 7);   // phys chunk
            s16x8 af[4], bfr[2];
#pragma unroll
            for (int i = 0; i < 4; ++i)
                af[i] = ((const s16x8*)(Us0 + (size_t)buf * bufU))[(arow + i * 16) * (BK / 8) + cx];
#pragma unroll
            for (int j = 0; j < 2; ++j)
                bfr[j] = ((const s16x8*)(Vs0 + (size_t)buf * bufV))[(brow + j * 16) * (BK / 8) + cx];
#pragma unroll
            for (int i = 0; i < 4; ++i)
#pragma unroll
                for (int j = 0; j < 2; ++j)
                    acc[i][j] = __builtin_amdgcn_mfma_f32_16x16x32_bf16(
                        af[i], bfr[j], acc[i][j], 0, 0, 0);
        }
        buf ^= 1;
    }

    // ---- epilogue ----  C/D layout: col=lane&15, row=(lane>>4)*4+r
    const int ldo = op.ldo;
    const int ccol = lane & 15;
    const int crow = (lane >> 4) * 4;

    if (op.OutB || op.OutF) {
#pragma unroll
        for (int i = 0; i < 4; ++i) {
#pragma unroll
            for (int j = 0; j < 2; ++j) {
                const int gr0 = bm * BM + wm + i * 16 + crow;
                const int gc = bn * 128 + wn + j * 16 + ccol;
                float v[4];
#pragma unroll
                for (int r = 0; r < 4; ++r) {
                    v[r] = acc[i][j][r];
                    if (op.Add) v[r] += bf16_to_f32(op.Add[(size_t)(gr0 + r) * ldo + gc]);
                }
                if (op.OutB) {
#pragma unroll
                    for (int r = 0; r < 4; ++r)
                        op.OutB[(size_t)(gr0 + r) * ldo + gc] = f32_to_bf16(v[r]);
                }
                if (op.OutF) {
#pragma unroll
                    for (int r = 0; r < 4; ++r)
                        op.OutF[(size_t)(gr0 + r) * ldo + gc] = v[r];
                }
            }
        }
    }

    // transposed bf16 via LDS bounce; T[col][row], stride 132 u16.
    if (op.OutT) {
        __syncthreads();                   // all K-loop LDS reads complete
        u16* T = (u16*)SMEM;               // 128*132*2 = 33792 B <= 64 KB
#pragma unroll
        for (int i = 0; i < 4; ++i) {
#pragma unroll
            for (int j = 0; j < 2; ++j) {
                const int c_ = wn + j * 16 + ccol;
                const int r_ = wm + i * 16 + crow;      // multiple of 4
                uint2 w;
                w.x = (u32)f32_to_bf16(acc[i][j][0]) | ((u32)f32_to_bf16(acc[i][j][1]) << 16);
                w.y = (u32)f32_to_bf16(acc[i][j][2]) | ((u32)f32_to_bf16(acc[i][j][3]) << 16);
                *(uint2*)&T[c_ * 132 + r_] = w;
            }
        }
        __syncthreads();
        const int cpart = t >> 4;          // 0..31: column within pass
        const int m = t & 15;              // 16 B chunk along the row
#pragma unroll
        for (int k2 = 0; k2 < 4; ++k2) {
            const int c_ = k2 * 32 + cpart;
            uint2 x = *(const uint2*)&T[c_ * 132 + m * 8];
            uint2 y = *(const uint2*)&T[c_ * 132 + m * 8 + 4];
            uint4 w; w.x = x.x; w.y = x.y; w.z = y.x; w.w = y.y;
            *(uint4*)&op.OutT[(size_t)(bn * 128 + c_) * ldo + bm * BM + m * 8] = w;
        }
    }
}

// R25 single-op kernel: 512 threads / 8 waves (4M x 2N, wave-tile 32x32,
// acc[2][2]), BM=128 BN=64, LDS 48 KB -> on 512-block grids 2 blocks/CU =
// 16 waves/CU = 4 waves/SIMD (the regime R23 proved ~5-8% better than the
// old 256-thread sm kernel's 2/SIMD). Per-acc K order identical -> same
// numerics. No OutT users among singles -> bounce pass dropped.
__global__ __launch_bounds__(512, 4) void stein_gemm_sg(GemmOp op0) {
    const GemmOp op = op0;
    int bm = blockIdx.x, bn = blockIdx.y;
    if (op.N >= 1024) {                       // XCD chunking (grid 16x32)
        const int orig = (int)blockIdx.x + ((int)blockIdx.y << 4);
        const int xcd = orig & 7, idx = orig >> 3;
        bm = (xcd & 3) * 4 + (idx & 3);
        bn = (xcd >> 2) * 16 + (idx >> 2);
    }
    if (bn * 64 >= op.N) return;

    __shared__ alignas(16) short SMEM[2 * BM * BK + 2 * 64 * BK];  // 48 KB
    short* Us0 = SMEM;
    short* Vs0 = SMEM + 2 * BM * BK;

    const int t = threadIdx.x;
    const int wave = t >> 6;                  // 0..7
    const int lane = t & 63;
    const int wm = (wave >> 1) * 32;          // 4 M-groups of 32 rows
    const int wn = (wave & 1) * 32;           // 2 N-groups of 32 cols

    // staging: wave w covers A rows [16w,16w+16) (2 ops) and B rows
    // [8w,8w+8) (1 op); 8 rows x 128 B per op.
    const int lrow8 = lane >> 3;
    const int lchunk = (lane & 7) ^ lrow8;
    const u16* gU = op.U + (size_t)(bm * BM + 16 * wave + lrow8) * op.ldu + lchunk * 8;
    const u16* gV = op.V + (size_t)(bn * 64 + 8 * wave + lrow8) * op.ldv + lchunk * 8;
    short* sU = Us0 + (16 * wave) * BK;
    short* sV = Vs0 + (8 * wave) * BK;
    const int bufU = BM * BK;
    const int bufV = 64 * BK;

    f32x4 acc[2][2];
#pragma unroll
    for (int i = 0; i < 2; ++i)
#pragma unroll
        for (int j = 0; j < 2; ++j) acc[i][j] = (f32x4){0.f, 0.f, 0.f, 0.f};

    const int arow = wm + (lane & 15);
    const int brow = wn + (lane & 15);

    // prologue: stage tile 0 into buffer 0
#pragma unroll
    for (int j = 0; j < 2; ++j)
        gld_lds16(gU + (size_t)(8 * j) * op.ldu, sU + j * 512);
    gld_lds16(gV, sV);

    int buf = 0;
    for (int kk = 0; kk < op.K; kk += BK) {
        __syncthreads();
        if (kk + BK < op.K) {
            const int kn = kk + BK;
            const int bo = buf ^ 1;
#pragma unroll
            for (int j = 0; j < 2; ++j)
                gld_lds16(gU + (size_t)(8 * j) * op.ldu + kn, sU + bo * bufU + j * 512);
            gld_lds16(gV + kn, sV + bo * bufV);
        }
#pragma unroll
        for (int s = 0; s < 2; ++s) {
            const int cx = (s * 4 + (lane >> 4)) ^ (lane & 7);
            s16x8 af[2], bfr[2];
#pragma unroll
            for (int i = 0; i < 2; ++i)
                af[i] = ((const s16x8*)(Us0 + (size_t)buf * bufU))[(arow + i * 16) * (BK / 8) + cx];
#pragma unroll
            for (int j = 0; j < 2; ++j)
                bfr[j] = ((const s16x8*)(Vs0 + (size_t)buf * bufV))[(brow + j * 16) * (BK / 8) + cx];
#pragma unroll
            for (int i = 0; i < 2; ++i)
#pragma unroll
                for (int j = 0; j < 2; ++j)
                    acc[i][j] = __builtin_amdgcn_mfma_f32_16x16x32_bf16(
                        af[i], bfr[j], acc[i][j], 0, 0, 0);
        }
        buf ^= 1;
    }

    const int ldo = op.ldo;
    const int ccol = lane & 15;
    const int crow = (lane >> 4) * 4;

#pragma unroll
    for (int i = 0; i < 2; ++i) {
#pragma unroll
        for (int j = 0; j < 2; ++j) {
            const int gr0 = bm * BM + wm + i * 16 + crow;
            const int gc = bn * 64 + wn + j * 16 + ccol;
            float v[4];
#pragma unroll
            for (int r = 0; r < 4; ++r) {
                v[r] = acc[i][j][r];
                if (op.Add) v[r] += bf16_to_f32(op.Add[(size_t)(gr0 + r) * ldo + gc]);
            }
            if (op.OutB) {
#pragma unroll
                for (int r = 0; r < 4; ++r)
                    op.OutB[(size_t)(gr0 + r) * ldo + gc] = f32_to_bf16(v[r]);
            }
            if (op.OutF) {
#pragma unroll
                for (int r = 0; r < 4; ++r)
                    op.OutF[(size_t)(gr0 + r) * ldo + gc] = v[r];
            }
        }
    }
}

static inline GemmOp mkop(const u16* U, const u16* V, int K, int ldu, int ldv,
                          const u16* Add, u16* OutB, u16* OutT, float* OutF,
                          int N = 2048, int ldo = 2048) {
    GemmOp o;
    o.U = U; o.V = V; o.Add = Add; o.OutB = OutB; o.OutT = OutT; o.OutF = OutF;
    o.K = K; o.ldu = ldu; o.ldv = ldv; o.N = N; o.ldo = ldo;
    return o;
}

extern "C" void kernel_launch(void* const* d_in, const int* in_sizes, int n_in,
                              void* d_out, int out_size, void* d_ws, size_t ws_size,
                              hipStream_t stream) {
    const float* A = (const float*)d_in[0];     // (2048, 2048)
    const float* A_F = (const float*)d_in[1];   // (2048, 2048)
    const float* C = (const float*)d_in[2];     // (512, 2048)
    const float* C_F = (const float*)d_in[3];   // (512, 2048)
    const int n = 2048, p = 512;
    (void)in_sizes; (void)n_in; (void)out_size; (void)ws_size;

    char* ws = (char*)d_ws;
    const size_t MB = 1u << 20;
    // ---- Smith squaring, 5 levels -> S_32 (tail bound: see R12 notes).
    // d0b-fold: R_1 = [CFT|W1] [CT|Y]^T in ONE K=1024 GEMM.
    // XT transpose-free via operand swap: (R A)^T = NT(U=A^T, V=R).
    // Asq swapped (U=A^T, V=A) so d1's two z's share the U stream.
    // R24: R carried in bf16 only (Rb); Rup in place Rb = bf16(BX+Rb).
    u16* AT   = (u16*)(ws + 0 * MB);    // A^T  bf16  (A_0 transposed form)
    u16* Ab   = (u16*)(ws + 8 * MB);    // A    bf16  (A_0 row form)
    u16* AFT  = (u16*)(ws + 16 * MB);   // B=A_F^T row bf16 (B_0 row form)
    u16* AFb  = (u16*)(ws + 24 * MB);   // A_F  bf16  (B_0 transposed form)
    u16* WYU  = (u16*)(ws + 32 * MB);   // 2048x1024: [CFT | W1=B C_F^T]
    u16* WYV  = (u16*)(ws + 36 * MB);   // 2048x1024: [CT  | Y=A^T C^T]
    u16* XT   = (u16*)(ws + 32 * MB);   // (R A_i)^T — overlaps WYU/WYV (dead after d0b)
    u16* Rb   = (u16*)(ws + 56 * MB);   // running R bf16 row
    u16* CFb  = (u16*)(ws + 64 * MB);   // C_F bf16 row (level 0 only)
    u16* Cb   = (u16*)(ws + 66 * MB);   // C   bf16 row (level 0 only)
    u16* Tb1  = (u16*)(ws + 68 * MB);   // ping-pong set 1: B_i row
    u16* TbT1 = (u16*)(ws + 76 * MB);   //                  B_i^T
    u16* Ub1  = (u16*)(ws + 84 * MB);   //                  A_i row
    u16* UbT1 = (u16*)(ws + 92 * MB);   //                  A_i^T   (top = 100 MB)

    // R25: fused prep — one launch, z in {A, A_F, C_F, C}.
    {
        PrepOp pA  = {A,   Ab,  AT,  n, n, n};
        PrepOp pAF = {A_F, AFb, AFT, n, n, n};
        PrepOp pCF = {C_F, CFb, WYU, p, n, 2 * p};
        PrepOp pC  = {C,   Cb,  WYV, p, n, 2 * p};
        stein_prep<<<dim3(64, 64, 4), dim3(32, 8), 0, stream>>>(pA, pAF, pCF, pC);
    }

    u16* Tb[2]  = {AFT, Tb1};
    u16* TbT[2] = {AFb, TbT1};
    u16* Ub[2]  = {Ab, Ub1};
    u16* UbT[2] = {AT, UbT1};

    dim3 blk8(512);
    dim3 g2(16, 16, 2), g4(16, 16, 4);
    dim3 gs(16, 32, 1);                 // sg kernel single-op grid

    // d0 (z=4): level-0 independent ops.
    {
        GemmOp oW1  = mkop(AFT, CFb, n, n, n, nullptr, WYU + p, nullptr, nullptr, p, 2 * p);
        GemmOp oY   = mkop(AT, Cb, n, n, n, nullptr, WYV + p, nullptr, nullptr, p, 2 * p);
        GemmOp oAsq = mkop(AT, Ab, n, n, n, nullptr, UbT1, Ub1, nullptr);   // swapped
        GemmOp oBsq = mkop(AFT, AFb, n, n, n, nullptr, Tb1, TbT1, nullptr);
        stein_gemm_w8<<<g4, blk8, 0, stream>>>(oW1, oY, oAsq, oBsq, oBsq);
    }
    // d0b: R_1 = [CFT|W1] [CT|Y]^T  (K=1024 concat = RHS + B RHS A)
    {
        GemmOp oR1 = mkop(WYU, WYV, 2 * p, 2 * p, 2 * p, nullptr, Rb, nullptr, nullptr);
        stein_gemm_sg<<<gs, blk8, 0, stream>>>(oR1);
    }

    // levels 1..3: full doubling, stream-sharing pairing.
    // Level 3 drops dead outputs (level 4 needs only UbT[0] and Tb[0]).
    for (int i = 1; i < 4; ++i) {
        const int c = i & 1, nx = c ^ 1;
        // d1: {XT = (R A_i)^T via swap, Asq swapped} — shared U = A_i^T.
        GemmOp oXT = mkop(UbT[c], Rb, n, n, n, nullptr, XT, nullptr, nullptr);
        GemmOp oAsq = mkop(UbT[c], Ub[c], n, n, n, nullptr, UbT[nx],
                           (i == 3) ? nullptr : Ub[nx], nullptr);
        stein_gemm_w8<<<g2, blk8, 0, stream>>>(oXT, oAsq, oAsq, oAsq, oAsq);
        // d2: {Rup = bf16(B_i X + Rb) in place, Bsq} — shared U stream = B_i.
        GemmOp oRup = mkop(Tb[c], XT, n, n, n, Rb, Rb, nullptr, nullptr);
        GemmOp oBsq = mkop(Tb[c], TbT[c], n, n, n, nullptr, Tb[nx],
                           (i == 3) ? nullptr : TbT[nx], nullptr);
        stein_gemm_w8<<<g2, blk8, 0, stream>>>(oRup, oBsq, oBsq, oBsq, oBsq);
    }

    // level 4 (final): S_32 = Rb + B_4 (R_4 A_4) -> d_out. A_4/B_4 in set 0.
    {
        GemmOp oXT = mkop(UbT[0], Rb, n, n, n, nullptr, XT, nullptr, nullptr);
        stein_gemm_sg<<<gs, blk8, 0, stream>>>(oXT);
        GemmOp oFin = mkop(Tb[0], XT, n, n, n, Rb, nullptr, nullptr, (float*)d_out);
        stein_gemm_sg<<<gs, blk8, 0, stream>>>(oFin);
    }
}